// Round 1
// baseline (270.160 us; speedup 1.0000x reference)
//
#include <hip/hip_runtime.h>

#define TH 4
#define W_ 1024
#define H_ 1024

__device__ __forceinline__ float wexp1(float zp, float iz, float kd, float kspat) {
    const float u = fmaf(zp, iz, -1.0f);
    return __builtin_amdgcn_exp2f(fmaf(u * kd, u, kspat));
}

// 5-tap depth-guided blur of (b,d) around center; taps m2,m1,[c],p1,p2
__device__ __forceinline__ void blur5(
    float zm2, float zm1, float zc, float zp1, float zp2,
    float bm2, float bm1, float bc, float bp1, float bp2,
    float dm2, float dm1, float dc, float dp1, float dp2,
    float kd, float ks1, float ks4,
    float& ob, float& od)
{
    const float iz = __builtin_amdgcn_rcpf(zc);
    const float w0 = wexp1(zm2, iz, kd, ks4);
    const float w1 = wexp1(zm1, iz, kd, ks1);
    const float w3 = wexp1(zp1, iz, kd, ks1);
    const float w4 = wexp1(zp2, iz, kd, ks4);
    const float wr = __builtin_amdgcn_rcpf(1.0f + w0 + w1 + w3 + w4);
    ob = fmaf(w0, bm2, fmaf(w1, bm1, fmaf(w3, bp1, fmaf(w4, bp2, bc)))) * wr;
    od = fmaf(w0, dm2, fmaf(w1, dm1, fmaf(w3, dp1, fmaf(w4, dp2, dc)))) * wr;
}

__device__ __forceinline__ float blend1(float bc, float dc, float bm, float dm,
                                        float de, float dke, float ce) {
    const float devb = __builtin_amdgcn_exp2f(
        de * __builtin_amdgcn_logf(fmaxf(fabsf(bc - bm), 1e-8f))) * ce;
    const float devd = fmaxf(__builtin_amdgcn_exp2f(
        de * __builtin_amdgcn_logf(fmaxf(fabsf(dc - dm), 1e-8f))), dke);
    const float wr = __builtin_amdgcn_rcpf(devb + devd);
    return fmaf(devd, bc, devb * dc) * wr;
}

// horizontal blur of row gy into pipeline slot (sb,sd,sz); 4 px at cols c..c+3
__device__ __forceinline__ void stage_row(
    int gy, const float* __restrict__ bB, const float* __restrict__ dB,
    const float* __restrict__ zB,
    int c, int colL2, int colR2, bool eL, bool eR,
    float kd, float ks1, float ks4,
    float4& sb, float4& sd, float4& sz)
{
    if ((unsigned)gy < (unsigned)H_) {   // block-uniform
        const size_t ro = (size_t)gy * W_;
        const float2 lb = *(const float2*)(bB + ro + colL2);
        const float4 cb = *(const float4*)(bB + ro + c);
        const float2 rb = *(const float2*)(bB + ro + colR2);
        const float2 ld = *(const float2*)(dB + ro + colL2);
        const float4 cd = *(const float4*)(dB + ro + c);
        const float2 rd = *(const float2*)(dB + ro + colR2);
        float2 lz = *(const float2*)(zB + ro + colL2);
        const float4 cz = *(const float4*)(zB + ro + c);
        float2 rz = *(const float2*)(zB + ro + colR2);
        // image-edge taps: poison depth -> |t| huge -> kd*t^2 = -inf -> w = 0
        // (matches the reference's zero-padding exactly)
        if (eL) { lz.x = 1e18f; lz.y = 1e18f; }
        if (eR) { rz.x = 1e18f; rz.y = 1e18f; }
        // window cols: lz(c-2,c-1) cz(c..c+3) rz(c+4,c+5)
        blur5(lz.x, lz.y, cz.x, cz.y, cz.z,  lb.x, lb.y, cb.x, cb.y, cb.z,
              ld.x, ld.y, cd.x, cd.y, cd.z,  kd, ks1, ks4, sb.x, sd.x);
        blur5(lz.y, cz.x, cz.y, cz.z, cz.w,  lb.y, cb.x, cb.y, cb.z, cb.w,
              ld.y, cd.x, cd.y, cd.z, cd.w,  kd, ks1, ks4, sb.y, sd.y);
        blur5(cz.x, cz.y, cz.z, cz.w, rz.x,  cb.x, cb.y, cb.z, cb.w, rb.x,
              cd.x, cd.y, cd.z, cd.w, rd.x,  kd, ks1, ks4, sb.z, sd.z);
        blur5(cz.y, cz.z, cz.w, rz.x, rz.y,  cb.y, cb.z, cb.w, rb.x, rb.y,
              cd.y, cd.z, cd.w, rd.x, rd.y,  kd, ks1, ks4, sb.w, sd.w);
        sz = cz;
    } else {
        // zero-pad row: z=0 -> vertical tap t=-1 -> w = exp2(kd+ks) = 0 exact
        sb = make_float4(0.f, 0.f, 0.f, 0.f);
        sd = make_float4(0.f, 0.f, 0.f, 0.f);
        sz = make_float4(0.f, 0.f, 0.f, 0.f);
    }
}

// stage row (y0+i-2) into slot S, then vertical blur + blend of row (y0+i-4)
#define STEP(S, S0, S1, S2, S3, S4, I)                                        \
  {                                                                           \
    stage_row(y0 + (I) - 2, bB, dB, zB, c, colL2, colR2, eL, eR,              \
              kd, ks1, ks4, pb[S], pd[S], pz[S]);                             \
    float4 bm, dm;                                                            \
    blur5(pz[S0].x, pz[S1].x, pz[S2].x, pz[S3].x, pz[S4].x,                   \
          pb[S0].x, pb[S1].x, pb[S2].x, pb[S3].x, pb[S4].x,                   \
          pd[S0].x, pd[S1].x, pd[S2].x, pd[S3].x, pd[S4].x,                   \
          kd, ks1, ks4, bm.x, dm.x);                                          \
    blur5(pz[S0].y, pz[S1].y, pz[S2].y, pz[S3].y, pz[S4].y,                   \
          pb[S0].y, pb[S1].y, pb[S2].y, pb[S3].y, pb[S4].y,                   \
          pd[S0].y, pd[S1].y, pd[S2].y, pd[S3].y, pd[S4].y,                   \
          kd, ks1, ks4, bm.y, dm.y);                                          \
    blur5(pz[S0].z, pz[S1].z, pz[S2].z, pz[S3].z, pz[S4].z,                   \
          pb[S0].z, pb[S1].z, pb[S2].z, pb[S3].z, pb[S4].z,                   \
          pd[S0].z, pd[S1].z, pd[S2].z, pd[S3].z, pd[S4].z,                   \
          kd, ks1, ks4, bm.z, dm.z);                                          \
    blur5(pz[S0].w, pz[S1].w, pz[S2].w, pz[S3].w, pz[S4].w,                   \
          pb[S0].w, pb[S1].w, pb[S2].w, pb[S3].w, pb[S4].w,                   \
          pd[S0].w, pd[S1].w, pd[S2].w, pd[S3].w, pd[S4].w,                   \
          kd, ks1, ks4, bm.w, dm.w);                                          \
    const size_t oo = (size_t)(y0 + (I) - 4) * W_ + c;                        \
    const float4 rb4 = *(const float4*)(bB + oo);                             \
    const float4 rd4 = *(const float4*)(dB + oo);                             \
    float4 res;                                                               \
    res.x = blend1(rb4.x, rd4.x, bm.x, dm.x, de, dke, ce);                    \
    res.y = blend1(rb4.y, rd4.y, bm.y, dm.y, de, dke, ce);                    \
    res.z = blend1(rb4.z, rd4.z, bm.z, dm.z, de, dke, ce);                    \
    res.w = blend1(rb4.w, rd4.w, bm.w, dm.w, de, dke, ce);                    \
    *(float4*)(outB + oo) = res;                                              \
  }

// TH=4: grid.y = 256 -> 2048 blocks = 8 blocks/CU = 32 waves/CU (100% fill).
// Halo recompute rises 1.5x -> 2.0x, but halo re-reads are L3 hits (96 MB < 256 MB).
__global__ __launch_bounds__(256, 8)
void bilateral_fused(const float* __restrict__ bright,
                     const float* __restrict__ dark,
                     const float* __restrict__ depths,
                     const float* __restrict__ p_dv,
                     const float* __restrict__ p_sv,
                     const float* __restrict__ p_de,
                     const float* __restrict__ p_deps,
                     const float* __restrict__ p_ce,
                     float* __restrict__ out)
{
    const float LOG2E = 1.44269504088896340736f;
    const float kd  = -LOG2E / (2.0f * p_dv[0]);   // ~ -1803
    const float ks  = -LOG2E / (2.0f * p_sv[0]);
    const float de  = p_de[0];
    const float dke = p_deps[0];
    const float ce  = p_ce[0];
    const float ks1 = ks;
    const float ks4 = 4.0f * ks;

    const int t  = threadIdx.x;           // 0..255
    const int c  = 4 * t;                 // cols c..c+3
    const int y0 = blockIdx.y * TH;

    const size_t plane = (size_t)H_ * W_;
    const float* bB = bright + (size_t)blockIdx.z * plane;
    const float* dB = dark   + (size_t)blockIdx.z * plane;
    const float* zB = depths + (size_t)blockIdx.z * plane;
    float*     outB = out    + (size_t)blockIdx.z * plane;

    const int  colL2 = max(c - 2, 0);        // float2 [c-2,c-1], 8B aligned
    const int  colR2 = min(c + 4, W_ - 2);   // float2 [c+4,c+5]
    const bool eL = (c == 0);
    const bool eR = (c + 4 >= W_);

    // 5-deep register pipeline: horizontally-blurred (b,d) + center depths
    float4 pb[5], pd[5], pz[5];

    // warm-up: steps i = 0..3 -> slots 0..3 (no output yet)
    stage_row(y0 - 2, bB, dB, zB, c, colL2, colR2, eL, eR, kd, ks1, ks4, pb[0], pd[0], pz[0]);
    stage_row(y0 - 1, bB, dB, zB, c, colL2, colR2, eL, eR, kd, ks1, ks4, pb[1], pd[1], pz[1]);
    stage_row(y0 + 0, bB, dB, zB, c, colL2, colR2, eL, eR, kd, ks1, ks4, pb[2], pd[2], pz[2]);
    stage_row(y0 + 1, bB, dB, zB, c, colL2, colR2, eL, eR, kd, ks1, ks4, pb[3], pd[3], pz[3]);

    // steady state: steps i = 4..7, fully static slot rotation (TH = 4)
    STEP(4, 0, 1, 2, 3, 4,  4)
    STEP(0, 1, 2, 3, 4, 0,  5)
    STEP(1, 2, 3, 4, 0, 1,  6)
    STEP(2, 3, 4, 0, 1, 2,  7)
}

extern "C" void kernel_launch(void* const* d_in, const int* in_sizes, int n_in,
                              void* d_out, int out_size, void* d_ws, size_t ws_size,
                              hipStream_t stream)
{
    const float* bright = (const float*)d_in[0];
    const float* dark   = (const float*)d_in[1];
    const float* depths = (const float*)d_in[2];
    const float* p_dv   = (const float*)d_in[3];
    const float* p_sv   = (const float*)d_in[4];
    const float* p_de   = (const float*)d_in[5];
    const float* p_deps = (const float*)d_in[6];
    const float* p_ce   = (const float*)d_in[7];
    float* out = (float*)d_out;

    const int B = in_sizes[0] / (H_ * W_);

    dim3 grid(1, H_ / TH, B);
    dim3 block(256);
    bilateral_fused<<<grid, block, 0, stream>>>(bright, dark, depths,
                                                p_dv, p_sv, p_de, p_deps, p_ce,
                                                out);
}

// Round 2
// 162.453 us; speedup vs baseline: 1.6630x; 1.6630x over previous
//
#include <hip/hip_runtime.h>

#define TH 4
#define W_ 1024
#define H_ 1024

__device__ __forceinline__ float wexp1(float zp, float iz, float kd, float kspat) {
    const float u = fmaf(zp, iz, -1.0f);
    return __builtin_amdgcn_exp2f(fmaf(u * kd, u, kspat));
}

// 5-tap depth-guided blur of (b,d) around center; taps m2,m1,[c],p1,p2
__device__ __forceinline__ void blur5(
    float zm2, float zm1, float zc, float zp1, float zp2,
    float bm2, float bm1, float bc, float bp1, float bp2,
    float dm2, float dm1, float dc, float dp1, float dp2,
    float kd, float ks1, float ks4,
    float& ob, float& od)
{
    const float iz = __builtin_amdgcn_rcpf(zc);
    const float w0 = wexp1(zm2, iz, kd, ks4);
    const float w1 = wexp1(zm1, iz, kd, ks1);
    const float w3 = wexp1(zp1, iz, kd, ks1);
    const float w4 = wexp1(zp2, iz, kd, ks4);
    const float wr = __builtin_amdgcn_rcpf(1.0f + w0 + w1 + w3 + w4);
    ob = fmaf(w0, bm2, fmaf(w1, bm1, fmaf(w3, bp1, fmaf(w4, bp2, bc)))) * wr;
    od = fmaf(w0, dm2, fmaf(w1, dm1, fmaf(w3, dp1, fmaf(w4, dp2, dc)))) * wr;
}

__device__ __forceinline__ float blend1(float bc, float dc, float bm, float dm,
                                        float de, float dke, float ce) {
    const float devb = __builtin_amdgcn_exp2f(
        de * __builtin_amdgcn_logf(fmaxf(fabsf(bc - bm), 1e-8f))) * ce;
    const float devd = fmaxf(__builtin_amdgcn_exp2f(
        de * __builtin_amdgcn_logf(fmaxf(fabsf(dc - dm), 1e-8f))), dke);
    const float wr = __builtin_amdgcn_rcpf(devb + devd);
    return fmaf(devd, bc, devb * dc) * wr;
}

// horizontal blur of row gy into pipeline slot (sb,sd,sz); 4 px at cols c..c+3
__device__ __forceinline__ void stage_row(
    int gy, const float* __restrict__ bB, const float* __restrict__ dB,
    const float* __restrict__ zB,
    int c, int colL2, int colR2, bool eL, bool eR,
    float kd, float ks1, float ks4,
    float4& sb, float4& sd, float4& sz)
{
    if ((unsigned)gy < (unsigned)H_) {   // block-uniform
        const size_t ro = (size_t)gy * W_;
        const float2 lb = *(const float2*)(bB + ro + colL2);
        const float4 cb = *(const float4*)(bB + ro + c);
        const float2 rb = *(const float2*)(bB + ro + colR2);
        const float2 ld = *(const float2*)(dB + ro + colL2);
        const float4 cd = *(const float4*)(dB + ro + c);
        const float2 rd = *(const float2*)(dB + ro + colR2);
        float2 lz = *(const float2*)(zB + ro + colL2);
        const float4 cz = *(const float4*)(zB + ro + c);
        float2 rz = *(const float2*)(zB + ro + colR2);
        // image-edge taps: poison depth -> |t| huge -> kd*t^2 = -inf -> w = 0
        // (matches the reference's zero-padding exactly)
        if (eL) { lz.x = 1e18f; lz.y = 1e18f; }
        if (eR) { rz.x = 1e18f; rz.y = 1e18f; }
        // window cols: lz(c-2,c-1) cz(c..c+3) rz(c+4,c+5)
        blur5(lz.x, lz.y, cz.x, cz.y, cz.z,  lb.x, lb.y, cb.x, cb.y, cb.z,
              ld.x, ld.y, cd.x, cd.y, cd.z,  kd, ks1, ks4, sb.x, sd.x);
        blur5(lz.y, cz.x, cz.y, cz.z, cz.w,  lb.y, cb.x, cb.y, cb.z, cb.w,
              ld.y, cd.x, cd.y, cd.z, cd.w,  kd, ks1, ks4, sb.y, sd.y);
        blur5(cz.x, cz.y, cz.z, cz.w, rz.x,  cb.x, cb.y, cb.z, cb.w, rb.x,
              cd.x, cd.y, cd.z, cd.w, rd.x,  kd, ks1, ks4, sb.z, sd.z);
        blur5(cz.y, cz.z, cz.w, rz.x, rz.y,  cb.y, cb.z, cb.w, rb.x, rb.y,
              cd.y, cd.z, cd.w, rd.x, rd.y,  kd, ks1, ks4, sb.w, sd.w);
        sz = cz;
    } else {
        // zero-pad row: z=0 -> vertical tap t=-1 -> w = exp2(kd+ks) = 0 exact
        sb = make_float4(0.f, 0.f, 0.f, 0.f);
        sd = make_float4(0.f, 0.f, 0.f, 0.f);
        sz = make_float4(0.f, 0.f, 0.f, 0.f);
    }
}

// stage row (y0+i-2) into slot S, then vertical blur + blend of row (y0+i-4)
#define STEP(S, S0, S1, S2, S3, S4, I)                                        \
  {                                                                           \
    stage_row(y0 + (I) - 2, bB, dB, zB, c, colL2, colR2, eL, eR,              \
              kd, ks1, ks4, pb[S], pd[S], pz[S]);                             \
    float4 bm, dm;                                                            \
    blur5(pz[S0].x, pz[S1].x, pz[S2].x, pz[S3].x, pz[S4].x,                   \
          pb[S0].x, pb[S1].x, pb[S2].x, pb[S3].x, pb[S4].x,                   \
          pd[S0].x, pd[S1].x, pd[S2].x, pd[S3].x, pd[S4].x,                   \
          kd, ks1, ks4, bm.x, dm.x);                                          \
    blur5(pz[S0].y, pz[S1].y, pz[S2].y, pz[S3].y, pz[S4].y,                   \
          pb[S0].y, pb[S1].y, pb[S2].y, pb[S3].y, pb[S4].y,                   \
          pd[S0].y, pd[S1].y, pd[S2].y, pd[S3].y, pd[S4].y,                   \
          kd, ks1, ks4, bm.y, dm.y);                                          \
    blur5(pz[S0].z, pz[S1].z, pz[S2].z, pz[S3].z, pz[S4].z,                   \
          pb[S0].z, pb[S1].z, pb[S2].z, pb[S3].z, pb[S4].z,                   \
          pd[S0].z, pd[S1].z, pd[S2].z, pd[S3].z, pd[S4].z,                   \
          kd, ks1, ks4, bm.z, dm.z);                                          \
    blur5(pz[S0].w, pz[S1].w, pz[S2].w, pz[S3].w, pz[S4].w,                   \
          pb[S0].w, pb[S1].w, pb[S2].w, pb[S3].w, pb[S4].w,                   \
          pd[S0].w, pd[S1].w, pd[S2].w, pd[S3].w, pd[S4].w,                   \
          kd, ks1, ks4, bm.w, dm.w);                                          \
    const size_t oo = (size_t)(y0 + (I) - 4) * W_ + c;                        \
    const float4 rb4 = *(const float4*)(bB + oo);                             \
    const float4 rd4 = *(const float4*)(dB + oo);                             \
    float4 res;                                                               \
    res.x = blend1(rb4.x, rd4.x, bm.x, dm.x, de, dke, ce);                    \
    res.y = blend1(rb4.y, rd4.y, bm.y, dm.y, de, dke, ce);                    \
    res.z = blend1(rb4.z, rd4.z, bm.z, dm.z, de, dke, ce);                    \
    res.w = blend1(rb4.w, rd4.w, bm.w, dm.w, de, dke, ce);                    \
    *(float4*)(outB + oo) = res;                                              \
  }

// TH=4: grid.y = 256 -> 2048 blocks = 8 blocks/CU candidate residency.
// __launch_bounds__(256, 4): min-4-waves/EU guarantee only -> allocator keeps
// VGPR=60 (Round-0 proven, no spills). 60 <= 64 so HW still allows 8 waves/SIMD;
// the runtime fills to 8 blocks/CU from the 2048-block grid on its own.
// (Round-1 lesson: (256,8) clamped VGPR to 32 -> pipeline spilled to scratch,
//  WRITE_SIZE 32->258 MB, 3x regression.)
__global__ __launch_bounds__(256, 4)
void bilateral_fused(const float* __restrict__ bright,
                     const float* __restrict__ dark,
                     const float* __restrict__ depths,
                     const float* __restrict__ p_dv,
                     const float* __restrict__ p_sv,
                     const float* __restrict__ p_de,
                     const float* __restrict__ p_deps,
                     const float* __restrict__ p_ce,
                     float* __restrict__ out)
{
    const float LOG2E = 1.44269504088896340736f;
    const float kd  = -LOG2E / (2.0f * p_dv[0]);   // ~ -1803
    const float ks  = -LOG2E / (2.0f * p_sv[0]);
    const float de  = p_de[0];
    const float dke = p_deps[0];
    const float ce  = p_ce[0];
    const float ks1 = ks;
    const float ks4 = 4.0f * ks;

    const int t  = threadIdx.x;           // 0..255
    const int c  = 4 * t;                 // cols c..c+3
    const int y0 = blockIdx.y * TH;

    const size_t plane = (size_t)H_ * W_;
    const float* bB = bright + (size_t)blockIdx.z * plane;
    const float* dB = dark   + (size_t)blockIdx.z * plane;
    const float* zB = depths + (size_t)blockIdx.z * plane;
    float*     outB = out    + (size_t)blockIdx.z * plane;

    const int  colL2 = max(c - 2, 0);        // float2 [c-2,c-1], 8B aligned
    const int  colR2 = min(c + 4, W_ - 2);   // float2 [c+4,c+5]
    const bool eL = (c == 0);
    const bool eR = (c + 4 >= W_);

    // 5-deep register pipeline: horizontally-blurred (b,d) + center depths
    float4 pb[5], pd[5], pz[5];

    // warm-up: steps i = 0..3 -> slots 0..3 (no output yet)
    stage_row(y0 - 2, bB, dB, zB, c, colL2, colR2, eL, eR, kd, ks1, ks4, pb[0], pd[0], pz[0]);
    stage_row(y0 - 1, bB, dB, zB, c, colL2, colR2, eL, eR, kd, ks1, ks4, pb[1], pd[1], pz[1]);
    stage_row(y0 + 0, bB, dB, zB, c, colL2, colR2, eL, eR, kd, ks1, ks4, pb[2], pd[2], pz[2]);
    stage_row(y0 + 1, bB, dB, zB, c, colL2, colR2, eL, eR, kd, ks1, ks4, pb[3], pd[3], pz[3]);

    // steady state: steps i = 4..7, fully static slot rotation (TH = 4)
    STEP(4, 0, 1, 2, 3, 4,  4)
    STEP(0, 1, 2, 3, 4, 0,  5)
    STEP(1, 2, 3, 4, 0, 1,  6)
    STEP(2, 3, 4, 0, 1, 2,  7)
}

extern "C" void kernel_launch(void* const* d_in, const int* in_sizes, int n_in,
                              void* d_out, int out_size, void* d_ws, size_t ws_size,
                              hipStream_t stream)
{
    const float* bright = (const float*)d_in[0];
    const float* dark   = (const float*)d_in[1];
    const float* depths = (const float*)d_in[2];
    const float* p_dv   = (const float*)d_in[3];
    const float* p_sv   = (const float*)d_in[4];
    const float* p_de   = (const float*)d_in[5];
    const float* p_deps = (const float*)d_in[6];
    const float* p_ce   = (const float*)d_in[7];
    float* out = (float*)d_out;

    const int B = in_sizes[0] / (H_ * W_);

    dim3 grid(1, H_ / TH, B);
    dim3 block(256);
    bilateral_fused<<<grid, block, 0, stream>>>(bright, dark, depths,
                                                p_dv, p_sv, p_de, p_deps, p_ce,
                                                out);
}

// Round 4
// 155.548 us; speedup vs baseline: 1.7368x; 1.0444x over previous
//
#include <hip/hip_runtime.h>

#define TH 8
#define W_ 1024
#define H_ 1024

__device__ __forceinline__ float wexp1(float zp, float iz, float kd, float kspat) {
    const float u = fmaf(zp, iz, -1.0f);
    return __builtin_amdgcn_exp2f(fmaf(u * kd, u, kspat));
}

// 5-tap depth-guided blur of (b,d) around center; taps m2,m1,[c],p1,p2
__device__ __forceinline__ void blur5(
    float zm2, float zm1, float zc, float zp1, float zp2,
    float bm2, float bm1, float bc, float bp1, float bp2,
    float dm2, float dm1, float dc, float dp1, float dp2,
    float kd, float ks1, float ks4,
    float& ob, float& od)
{
    const float iz = __builtin_amdgcn_rcpf(zc);
    const float w0 = wexp1(zm2, iz, kd, ks4);
    const float w1 = wexp1(zm1, iz, kd, ks1);
    const float w3 = wexp1(zp1, iz, kd, ks1);
    const float w4 = wexp1(zp2, iz, kd, ks4);
    const float wr = __builtin_amdgcn_rcpf(1.0f + w0 + w1 + w3 + w4);
    ob = fmaf(w0, bm2, fmaf(w1, bm1, fmaf(w3, bp1, fmaf(w4, bp2, bc)))) * wr;
    od = fmaf(w0, dm2, fmaf(w1, dm1, fmaf(w3, dp1, fmaf(w4, dp2, dc)))) * wr;
}

__device__ __forceinline__ float blend1(float bc, float dc, float bm, float dm,
                                        float de, float dke, float ce) {
    const float devb = __builtin_amdgcn_exp2f(
        de * __builtin_amdgcn_logf(fmaxf(fabsf(bc - bm), 1e-8f))) * ce;
    const float devd = fmaxf(__builtin_amdgcn_exp2f(
        de * __builtin_amdgcn_logf(fmaxf(fabsf(dc - dm), 1e-8f))), dke);
    const float wr = __builtin_amdgcn_rcpf(devb + devd);
    return fmaf(devd, bc, devb * dc) * wr;
}

// raw (unblurred) row data for 4 px + 2-px halos, 3 arrays: 24 floats in VGPRs
struct Raw {
    float2 lb, rb, ld, rd, lz, rz;
    float4 cb, cd, cz;
};

// issue the 9 vector loads for row gy; NO dependent compute here.
// (Round-2 lesson: load and h-blur in the same step serializes each step on
//  memory latency. Loads issued here are consumed one full step later.)
__device__ __forceinline__ void load_raw(
    int gy, const float* __restrict__ bB, const float* __restrict__ dB,
    const float* __restrict__ zB, int c, int colL2, int colR2, Raw& r)
{
    if ((unsigned)gy < (unsigned)H_) {   // block-uniform branch
        const size_t ro = (size_t)gy * W_;
        r.lz = *(const float2*)(zB + ro + colL2);
        r.cz = *(const float4*)(zB + ro + c);
        r.rz = *(const float2*)(zB + ro + colR2);
        r.lb = *(const float2*)(bB + ro + colL2);
        r.cb = *(const float4*)(bB + ro + c);
        r.rb = *(const float2*)(bB + ro + colR2);
        r.ld = *(const float2*)(dB + ro + colL2);
        r.cd = *(const float4*)(dB + ro + c);
        r.rd = *(const float2*)(dB + ro + colR2);
    }
}

// pure-VALU horizontal blur of a previously loaded raw row -> pipeline slot
__device__ __forceinline__ void hblur_raw(
    int gy, const Raw& r, bool eL, bool eR,
    float kd, float ks1, float ks4,
    float4& sb, float4& sd, float4& sz)
{
    if ((unsigned)gy < (unsigned)H_) {
        float2 lz = r.lz, rz = r.rz;
        // image-edge taps: poison depth -> |t| huge -> kd*t^2 = -inf -> w = 0
        if (eL) { lz.x = 1e18f; lz.y = 1e18f; }
        if (eR) { rz.x = 1e18f; rz.y = 1e18f; }
        blur5(lz.x, lz.y, r.cz.x, r.cz.y, r.cz.z,
              r.lb.x, r.lb.y, r.cb.x, r.cb.y, r.cb.z,
              r.ld.x, r.ld.y, r.cd.x, r.cd.y, r.cd.z,
              kd, ks1, ks4, sb.x, sd.x);
        blur5(lz.y, r.cz.x, r.cz.y, r.cz.z, r.cz.w,
              r.lb.y, r.cb.x, r.cb.y, r.cb.z, r.cb.w,
              r.ld.y, r.cd.x, r.cd.y, r.cd.z, r.cd.w,
              kd, ks1, ks4, sb.y, sd.y);
        blur5(r.cz.x, r.cz.y, r.cz.z, r.cz.w, rz.x,
              r.cb.x, r.cb.y, r.cb.z, r.cb.w, r.rb.x,
              r.cd.x, r.cd.y, r.cd.z, r.cd.w, r.rd.x,
              kd, ks1, ks4, sb.z, sd.z);
        blur5(r.cz.y, r.cz.z, r.cz.w, rz.x, rz.y,
              r.cb.y, r.cb.z, r.cb.w, r.rb.x, r.rb.y,
              r.cd.y, r.cd.z, r.cd.w, r.rd.x, r.rd.y,
              kd, ks1, ks4, sb.w, sd.w);
        sz = r.cz;
    } else {
        // zero-pad row: z=0 -> vertical tap t=-1 -> w = exp2(kd+ks) = 0 exact
        sb = make_float4(0.f, 0.f, 0.f, 0.f);
        sd = make_float4(0.f, 0.f, 0.f, 0.f);
        sz = make_float4(0.f, 0.f, 0.f, 0.f);
    }
}

// warm-up step I: h-blur row (y0+I-2) from R into slot S, prefetch row (y0+I-1)
#define WSTEP(S, I)                                                           \
  {                                                                           \
    hblur_raw(y0 + (I) - 2, R, eL, eR, kd, ks1, ks4, pb[S], pd[S], pz[S]);    \
    load_raw(y0 + (I) - 1, bB, dB, zB, c, colL2, colR2, R);                   \
  }

// full step I: h-blur row (y0+I-2) -> slot S, prefetch row (y0+I-1),
// then v-blur + blend + store output row (y0+I-4) from slots S0..S4.
// The v-blur/blend (~500 VALU cycles) covers the latency of the loads
// issued this step; the waitcnt for R sits at the TOP of the NEXT step.
#define FSTEP(S, S0, S1, S2, S3, S4, I, PREF)                                 \
  {                                                                           \
    hblur_raw(y0 + (I) - 2, R, eL, eR, kd, ks1, ks4, pb[S], pd[S], pz[S]);    \
    if (PREF) load_raw(y0 + (I) - 1, bB, dB, zB, c, colL2, colR2, R);         \
    const size_t oo = (size_t)(y0 + (I) - 4) * W_ + c;                        \
    const float4 rb4 = *(const float4*)(bB + oo);                             \
    const float4 rd4 = *(const float4*)(dB + oo);                             \
    float4 bm, dm;                                                            \
    blur5(pz[S0].x, pz[S1].x, pz[S2].x, pz[S3].x, pz[S4].x,                   \
          pb[S0].x, pb[S1].x, pb[S2].x, pb[S3].x, pb[S4].x,                   \
          pd[S0].x, pd[S1].x, pd[S2].x, pd[S3].x, pd[S4].x,                   \
          kd, ks1, ks4, bm.x, dm.x);                                          \
    blur5(pz[S0].y, pz[S1].y, pz[S2].y, pz[S3].y, pz[S4].y,                   \
          pb[S0].y, pb[S1].y, pb[S2].y, pb[S3].y, pb[S4].y,                   \
          pd[S0].y, pd[S1].y, pd[S2].y, pd[S3].y, pd[S4].y,                   \
          kd, ks1, ks4, bm.y, dm.y);                                          \
    blur5(pz[S0].z, pz[S1].z, pz[S2].z, pz[S3].z, pz[S4].z,                   \
          pb[S0].z, pb[S1].z, pb[S2].z, pb[S3].z, pb[S4].z,                   \
          pd[S0].z, pd[S1].z, pd[S2].z, pd[S3].z, pd[S4].z,                   \
          kd, ks1, ks4, bm.z, dm.z);                                          \
    blur5(pz[S0].w, pz[S1].w, pz[S2].w, pz[S3].w, pz[S4].w,                   \
          pb[S0].w, pb[S1].w, pb[S2].w, pb[S3].w, pb[S4].w,                   \
          pd[S0].w, pd[S1].w, pd[S2].w, pd[S3].w, pd[S4].w,                   \
          kd, ks1, ks4, bm.w, dm.w);                                          \
    float4 res;                                                               \
    res.x = blend1(rb4.x, rd4.x, bm.x, dm.x, de, dke, ce);                    \
    res.y = blend1(rb4.y, rd4.y, bm.y, dm.y, de, dke, ce);                    \
    res.z = blend1(rb4.z, rd4.z, bm.z, dm.z, de, dke, ce);                    \
    res.w = blend1(rb4.w, rd4.w, bm.w, dm.w, de, dke, ce);                    \
    *(float4*)(outB + oo) = res;                                              \
  }

// TH=8 (back from 4): halo recompute 1.5x, FETCH ~= ideal 99 MB (Round-0 data).
// Occupancy was proven NOT grid-limited (Round 2: 2048 blocks, still 33%);
// the lever is per-wave ILP via the decoupled load->consume pipeline.
// __launch_bounds__(256,4): allocator budget 128 VGPR — expected use ~96-110.
// (Round-1 lesson: (256,8) clamps to 32 VGPR -> scratch spills, 3x regression.)
__global__ __launch_bounds__(256, 4)
void bilateral_fused(const float* __restrict__ bright,
                     const float* __restrict__ dark,
                     const float* __restrict__ depths,
                     const float* __restrict__ p_dv,
                     const float* __restrict__ p_sv,
                     const float* __restrict__ p_de,
                     const float* __restrict__ p_deps,
                     const float* __restrict__ p_ce,
                     float* __restrict__ out)
{
    const float LOG2E = 1.44269504088896340736f;
    const float kd  = -LOG2E / (2.0f * p_dv[0]);   // ~ -1803
    const float ks  = -LOG2E / (2.0f * p_sv[0]);
    const float de  = p_de[0];
    const float dke = p_deps[0];
    const float ce  = p_ce[0];
    const float ks1 = ks;
    const float ks4 = 4.0f * ks;

    const int t  = threadIdx.x;           // 0..255
    const int c  = 4 * t;                 // cols c..c+3
    const int y0 = blockIdx.y * TH;

    const size_t plane = (size_t)H_ * W_;
    const float* bB = bright + (size_t)blockIdx.z * plane;
    const float* dB = dark   + (size_t)blockIdx.z * plane;
    const float* zB = depths + (size_t)blockIdx.z * plane;
    float*     outB = out    + (size_t)blockIdx.z * plane;

    const int  colL2 = max(c - 2, 0);        // float2 [c-2,c-1], 8B aligned
    const int  colR2 = min(c + 4, W_ - 2);   // float2 [c+4,c+5]
    const bool eL = (c == 0);
    const bool eR = (c + 4 >= W_);

    // 5-deep register pipeline of horizontally-blurred rows + center depths,
    // plus a 1-step-ahead raw-load buffer R (24 floats).
    float4 pb[5], pd[5], pz[5];
    Raw R;

    // prologue: issue loads for the first staged row (y0-2)
    load_raw(y0 - 2, bB, dB, zB, c, colL2, colR2, R);

    // warm-up: steps 0..3 stage rows y0-2 .. y0+1 into slots 0..3
    WSTEP(0, 0)
    WSTEP(1, 1)
    WSTEP(2, 2)
    WSTEP(3, 3)

    // steady state: steps 4..11, outputs rows y0 .. y0+7 (TH = 8)
    FSTEP(4, 0, 1, 2, 3, 4,  4, 1)
    FSTEP(0, 1, 2, 3, 4, 0,  5, 1)
    FSTEP(1, 2, 3, 4, 0, 1,  6, 1)
    FSTEP(2, 3, 4, 0, 1, 2,  7, 1)
    FSTEP(3, 4, 0, 1, 2, 3,  8, 1)
    FSTEP(4, 0, 1, 2, 3, 4,  9, 1)
    FSTEP(0, 1, 2, 3, 4, 0, 10, 1)
    FSTEP(1, 2, 3, 4, 0, 1, 11, 0)   // last step: no prefetch
}

extern "C" void kernel_launch(void* const* d_in, const int* in_sizes, int n_in,
                              void* d_out, int out_size, void* d_ws, size_t ws_size,
                              hipStream_t stream)
{
    const float* bright = (const float*)d_in[0];
    const float* dark   = (const float*)d_in[1];
    const float* depths = (const float*)d_in[2];
    const float* p_dv   = (const float*)d_in[3];
    const float* p_sv   = (const float*)d_in[4];
    const float* p_de   = (const float*)d_in[5];
    const float* p_deps = (const float*)d_in[6];
    const float* p_ce   = (const float*)d_in[7];
    float* out = (float*)d_out;

    const int B = in_sizes[0] / (H_ * W_);

    dim3 grid(1, H_ / TH, B);
    dim3 block(256);
    bilateral_fused<<<grid, block, 0, stream>>>(bright, dark, depths,
                                                p_dv, p_sv, p_de, p_deps, p_ce,
                                                out);
}